// Round 3
// baseline (978.466 us; speedup 1.0000x reference)
//
#include <hip/hip_runtime.h>

#define N_NODES 100000
#define N_EDGES 1600000
#define D_IN    256
#define D_HID   64
#define D_OUT   40
#define PROP_N  16

typedef short short8 __attribute__((ext_vector_type(8)));   // 8 bf16 (4 VGPRs)
typedef float f32x4  __attribute__((ext_vector_type(4)));   // MFMA accumulator

// ---- fp8 (OCP e4m3) helpers: HW convert, RNE, saturating ------------------
__device__ __forceinline__ unsigned char f32_to_fp8(float f) {
    int p = __builtin_amdgcn_cvt_pk_fp8_f32(f, f, 0, false);
    return (unsigned char)(p & 0xff);
}
// ---- bf16 helpers (RNE) ---------------------------------------------------
__device__ __forceinline__ unsigned short f32_to_bf16(float f) {
    unsigned int u = __float_as_uint(f);
    unsigned int r = (u + 0x7fffu + ((u >> 16) & 1u)) >> 16;
    return (unsigned short)r;
}
__device__ __forceinline__ unsigned int f32x2_to_bf16x2(float lo, float hi) {
    return (unsigned int)f32_to_bf16(lo) | ((unsigned int)f32_to_bf16(hi) << 16);
}
// decode packed edge: bits[31:15]=col, bits[14:0]=bf16(val) without sign
__device__ __forceinline__ float edge_val(unsigned p) {
    return __uint_as_float((p & 0x7fffu) << 16);
}
// 4-feature fp8 FMA: b holds 4 fp8 bytes
__device__ __forceinline__ void fma4(float4& a, float v, unsigned b) {
    a.x = fmaf(v, __builtin_amdgcn_cvt_f32_fp8((int)b, 0), a.x);
    a.y = fmaf(v, __builtin_amdgcn_cvt_f32_fp8((int)b, 1), a.y);
    a.z = fmaf(v, __builtin_amdgcn_cvt_f32_fp8((int)b, 2), a.z);
    a.w = fmaf(v, __builtin_amdgcn_cvt_f32_fp8((int)b, 3), a.w);
}

// ---------------------------------------------------------------------------
// Kernel 1: CSR row_ptr from sorted edge_row via binary search.
// ---------------------------------------------------------------------------
__global__ __launch_bounds__(256) void build_rowptr(const int* __restrict__ erow,
                                                    int* __restrict__ rp) {
    int r = blockIdx.x * blockDim.x + threadIdx.x;
    if (r > N_NODES) return;
    int lo = 0, hi = N_EDGES;
    while (lo < hi) {
        int mid = (lo + hi) >> 1;
        if (erow[mid] < r) lo = mid + 1; else hi = mid;
    }
    rp[r] = lo;
}

// ---------------------------------------------------------------------------
// Kernel 1b: pack (col, val) into ONE dword.
//   bits[31:15] = col (100000 < 2^17), bits[14:0] = bf16(val) sans sign.
// ---------------------------------------------------------------------------
__global__ __launch_bounds__(256) void pack_edges4(const int* __restrict__ ecol,
                                                   const float* __restrict__ evalv,
                                                   unsigned* __restrict__ ep4) {
    int i = blockIdx.x * blockDim.x + threadIdx.x;
    if (i >= N_EDGES) return;
    unsigned bf = f32_to_bf16(evalv[i]);
    ep4[i] = ((unsigned)ecol[i] << 15) | (bf & 0x7fffu);
}

// ---------------------------------------------------------------------------
// Kernel 1c: W1 [256][64] fp32 -> W1T [64][256] bf16 (for MFMA B-fragments).
// ---------------------------------------------------------------------------
__global__ __launch_bounds__(256) void prep_w1t(const float* __restrict__ W1,
                                                unsigned short* __restrict__ W1T) {
    int i = blockIdx.x * 256 + threadIdx.x;           // 16384 elements
    if (i >= D_IN * D_HID) return;
    int k = i >> 6, n = i & 63;
    W1T[n * 256 + k] = f32_to_bf16(W1[i]);
}

// ---------------------------------------------------------------------------
// Kernel 2 (MFMA): h = x @ W1 + b1 ; Y0f = h ; Y08 planes ; src = 0.5*diag*h
// CHANGE vs R2: K=256 reduction split across 2 waves (128 each), partials
// combined through a conflict-free [16][64] f32 LDS buffer. Halves the
// per-wave serial load->pack->MFMA chain (the R2 counters showed everything
// idle: 22% HBM / 6% VALU / 2% MFMA => latency-chain bound) and doubles
// wave count 6250 -> 12500.
// Epilogue additionally writes fp8 into two 3.2MB feature PLANES
// (cols 0-31 -> plane a, 32-63 -> plane b) for the split prop kernels.
// ---------------------------------------------------------------------------
__global__ __launch_bounds__(128) void mlp1(const float* __restrict__ x,
                                            const unsigned short* __restrict__ W1T,
                                            const float* __restrict__ b1,
                                            const float* __restrict__ diag,
                                            float* __restrict__ Y0f,
                                            unsigned char* __restrict__ Y0a,
                                            unsigned char* __restrict__ Y0b,
                                            float* __restrict__ src) {
    const int tid   = threadIdx.x;
    const int lane  = tid & 63;
    const int kh    = tid >> 6;             // K-half: 0 -> k 0..127, 1 -> 128..255
    const int l15   = lane & 15;
    const int quad  = lane >> 4;
    const int mbase = blockIdx.x * 16;      // 6250 * 16 == 100000 exactly

    f32x4 acc[4] = {};
    const float* xrow = x + (size_t)(mbase + l15) * D_IN + kh * 128 + quad * 8;

    #pragma unroll
    for (int ks = 0; ks < 4; ++ks) {
        float4 f0 = *(const float4*)(xrow + ks * 32);
        float4 f1 = *(const float4*)(xrow + ks * 32 + 4);
        union { short8 v; unsigned int u[4]; } a;
        a.u[0] = f32x2_to_bf16x2(f0.x, f0.y);
        a.u[1] = f32x2_to_bf16x2(f0.z, f0.w);
        a.u[2] = f32x2_to_bf16x2(f1.x, f1.y);
        a.u[3] = f32x2_to_bf16x2(f1.z, f1.w);

        #pragma unroll
        for (int ct = 0; ct < 4; ++ct) {
            short8 b = *(const short8*)(W1T + (ct * 16 + l15) * 256 +
                                        kh * 128 + ks * 32 + quad * 8);
            acc[ct] = __builtin_amdgcn_mfma_f32_16x16x32_bf16(a.v, b, acc[ct], 0, 0, 0);
        }
    }

    // cross-wave reduction: wave1 -> LDS, wave0 adds. [16][64] f32: lane ->
    // bank lane%32, 2-way aliasing (free). 16 ds_write_b32 / ds_read_b32.
    __shared__ float red[16][64];
    if (kh == 1) {
        #pragma unroll
        for (int ct = 0; ct < 4; ++ct)
            #pragma unroll
            for (int r = 0; r < 4; ++r)
                red[ct * 4 + r][lane] = acc[ct][r];
    }
    __syncthreads();
    if (kh == 1) return;

    float bias[4];
    #pragma unroll
    for (int ct = 0; ct < 4; ++ct) bias[ct] = b1[ct * 16 + l15];

    #pragma unroll
    for (int reg = 0; reg < 4; ++reg) {
        const int mr = mbase + quad * 4 + reg;
        const float dg = diag[mr];
        #pragma unroll
        for (int ct = 0; ct < 4; ++ct) {
            const int col = ct * 16 + l15;
            const float h = acc[ct][reg] + red[ct * 4 + reg][lane] + bias[ct];
            const size_t idx = (size_t)mr * 64 + col;
            Y0f[idx] = h;
            src[idx] = 0.5f * dg * h;
            unsigned char h8 = f32_to_fp8(h);
            if (col < 32) Y0a[(size_t)mr * 32 + col]        = h8;
            else          Y0b[(size_t)mr * 32 + (col - 32)] = h8;
        }
    }
}

// ---------------------------------------------------------------------------
// Kernel 3: HALF a propagation step (features [foff, foff+32) for all nodes).
// THE change this round: the gather target is a 3.2 MB plane that fits the
// 4 MiB per-XCD L2, so the 1.6M line-requests/pass are L2 hits (~200 cyc)
// instead of LLC misses (~600 cyc). R0-R2 established the kernel is bound
// by line-request count x service latency / MSHR (depth and instruction
// count changes were null); latency is the only remaining lever.
// 8 rows/wave, 8 lanes/row, lane owns 4 features; plane row = 32 B.
// ---------------------------------------------------------------------------
__global__ __launch_bounds__(256) void prop_half(const float* __restrict__ Yf,
                                                 const unsigned char* __restrict__ Y8p,
                                                 const float* __restrict__ src,
                                                 float* __restrict__ Yof,
                                                 unsigned char* __restrict__ Yo8p,
                                                 const int* __restrict__ rp,
                                                 const unsigned* __restrict__ ep4,
                                                 const int foff) {
    const int wid  = blockIdx.x * 4 + (threadIdx.x >> 6);   // 12500 waves
    const int lane = threadIdx.x & 63;
    const int g    = lane >> 3;         // row group 0..7
    const int fl   = lane & 7;          // feature-quad (features foff+fl*4..+3)
    const int row  = wid * 8 + g;       // exact: 100000 = 8 * 12500

    const int e0 = rp[row];
    const int e1 = rp[row + 1];

    const size_t fb = (size_t)row * 64 + foff + fl * 4;
    const float4 yself = *(const float4*)(Yf + fb);
    const float4 sv    = *(const float4*)(src + fb);
    const unsigned char* Y8f = Y8p + fl * 4;

    float4 acc0 = make_float4(0.f, 0.f, 0.f, 0.f);
    float4 acc1 = acc0, acc2 = acc0, acc3 = acc0;

    int e = e0;
    // scalar head until e is 4-aligned (16B-aligned uint4 loads)
    int ea = (e0 + 3) & ~3;
    if (ea > e1) ea = e1;
    for (; e < ea; ++e) {
        unsigned p = ep4[e];
        unsigned b = *(const unsigned*)(Y8f + ((size_t)(p >> 15) << 5));
        fma4(acc0, edge_val(p), b);
    }
    for (; e + 4 <= e1; e += 4) {
        uint4 pa = *(const uint4*)(ep4 + e);
        unsigned b0 = *(const unsigned*)(Y8f + ((size_t)(pa.x >> 15) << 5));
        unsigned b1 = *(const unsigned*)(Y8f + ((size_t)(pa.y >> 15) << 5));
        unsigned b2 = *(const unsigned*)(Y8f + ((size_t)(pa.z >> 15) << 5));
        unsigned b3 = *(const unsigned*)(Y8f + ((size_t)(pa.w >> 15) << 5));
        fma4(acc0, edge_val(pa.x), b0);
        fma4(acc1, edge_val(pa.y), b1);
        fma4(acc2, edge_val(pa.z), b2);
        fma4(acc3, edge_val(pa.w), b3);
    }
    for (; e < e1; ++e) {
        unsigned p = ep4[e];
        unsigned b = *(const unsigned*)(Y8f + ((size_t)(p >> 15) << 5));
        fma4(acc0, edge_val(p), b);
    }

    float4 accs;
    accs.x = (acc0.x + acc1.x) + (acc2.x + acc3.x);
    accs.y = (acc0.y + acc1.y) + (acc2.y + acc3.y);
    accs.z = (acc0.z + acc1.z) + (acc2.z + acc3.z);
    accs.w = (acc0.w + acc1.w) + (acc2.w + acc3.w);

    float4 o;
    o.x = fmaf(0.5f, yself.x, fmaf(0.5f, accs.x, sv.x));
    o.y = fmaf(0.5f, yself.y, fmaf(0.5f, accs.y, sv.y));
    o.z = fmaf(0.5f, yself.z, fmaf(0.5f, accs.z, sv.z));
    o.w = fmaf(0.5f, yself.w, fmaf(0.5f, accs.w, sv.w));

    *(float4*)(Yof + fb) = o;
    int pk = __builtin_amdgcn_cvt_pk_fp8_f32(o.x, o.y, 0, false);   // bytes 0,1
    pk     = __builtin_amdgcn_cvt_pk_fp8_f32(o.z, o.w, pk, true);   // bytes 2,3
    *(unsigned*)(Yo8p + (size_t)row * 32 + fl * 4) = (unsigned)pk;
}

// ---------------------------------------------------------------------------
// Kernel 4: out = relu(Y) @ W2 + b2.  One node per thread, 40 accumulators.
// ---------------------------------------------------------------------------
__global__ __launch_bounds__(256) void mlp2(const float* __restrict__ Y,
                                            const float* __restrict__ W2,
                                            const float* __restrict__ b2,
                                            float* __restrict__ out) {
    __shared__ float W2s[D_HID * D_OUT];
    __shared__ float b2s[D_OUT];
    int tid = threadIdx.x;
    for (int i = tid; i < D_HID * D_OUT; i += 256) W2s[i] = W2[i];
    if (tid < D_OUT) b2s[tid] = b2[tid];
    __syncthreads();

    int n = blockIdx.x * 256 + tid;
    if (n >= N_NODES) return;

    float acc[D_OUT];
    #pragma unroll
    for (int o = 0; o < D_OUT; ++o) acc[o] = b2s[o];

    const float4* Y4 = (const float4*)(Y + (size_t)n * 64);
    #pragma unroll 4
    for (int k4 = 0; k4 < 16; ++k4) {
        float4 y = Y4[k4];
        float ys[4];
        ys[0] = fmaxf(y.x, 0.0f); ys[1] = fmaxf(y.y, 0.0f);
        ys[2] = fmaxf(y.z, 0.0f); ys[3] = fmaxf(y.w, 0.0f);
        #pragma unroll
        for (int j = 0; j < 4; ++j) {
            int k = k4 * 4 + j;
            #pragma unroll
            for (int o = 0; o < D_OUT; ++o)
                acc[o] = fmaf(ys[j], W2s[k * D_OUT + o], acc[o]);
        }
    }

    float4* o4 = (float4*)(out + (size_t)n * D_OUT);
    #pragma unroll
    for (int q = 0; q < 10; ++q)
        o4[q] = make_float4(acc[4 * q], acc[4 * q + 1], acc[4 * q + 2], acc[4 * q + 3]);
}

// ---------------------------------------------------------------------------
extern "C" void kernel_launch(void* const* d_in, const int* in_sizes, int n_in,
                              void* d_out, int out_size, void* d_ws, size_t ws_size,
                              hipStream_t stream) {
    const float* x     = (const float*)d_in[0];
    const int*   erow  = (const int*)  d_in[1];
    const int*   ecol  = (const int*)  d_in[2];
    const float* evalv = (const float*)d_in[3];
    const float* diag  = (const float*)d_in[4];
    const float* W1    = (const float*)d_in[5];
    const float* b1    = (const float*)d_in[6];
    const float* W2    = (const float*)d_in[7];
    const float* b2    = (const float*)d_in[8];
    float* out = (float*)d_out;

    // workspace: Y0f|Y1f|src (fp32) | 4 fp8 planes [N][32] | ep4 | rp | W1T
    const size_t NV = (size_t)N_NODES * D_HID;
    const size_t NP = (size_t)N_NODES * 32;
    float*          Y0f = (float*)d_ws;
    float*          Y1f = Y0f + NV;
    float*          src = Y1f + NV;
    unsigned char*  P0a = (unsigned char*)(src + NV);
    unsigned char*  P0b = P0a + NP;
    unsigned char*  P1a = P0b + NP;
    unsigned char*  P1b = P1a + NP;
    unsigned*       ep4 = (unsigned*)(P1b + NP);
    int*            rp  = (int*)(ep4 + N_EDGES);
    unsigned short* W1T = (unsigned short*)
        (((unsigned long long)(rp + N_NODES + 1) + 15ull) & ~15ull);

    build_rowptr<<<(N_NODES + 1 + 255) / 256, 256, 0, stream>>>(erow, rp);
    pack_edges4<<<(N_EDGES + 255) / 256, 256, 0, stream>>>(ecol, evalv, ep4);
    prep_w1t<<<(D_IN * D_HID + 255) / 256, 256, 0, stream>>>(W1, W1T);
    mlp1<<<N_NODES / 16, 128, 0, stream>>>(x, W1T, b1, diag, Y0f, P0a, P0b, src);

    float*         Yf[2] = {Y0f, Y1f};
    unsigned char* Pa[2] = {P0a, P1a};
    unsigned char* Pb[2] = {P0b, P1b};
    for (int i = 0; i < PROP_N; ++i) {
        const int c = i & 1, n = (i + 1) & 1;
        prop_half<<<N_NODES / 32, 256, 0, stream>>>(
            Yf[c], Pa[c], src, Yf[n], Pa[n], rp, ep4, 0);
        prop_half<<<N_NODES / 32, 256, 0, stream>>>(
            Yf[c], Pb[c], src, Yf[n], Pb[n], rp, ep4, 32);
    }
    // PROP_N even -> final fp32 result in Y0f
    mlp2<<<(N_NODES + 255) / 256, 256, 0, stream>>>(Y0f, W2, b2, out);
}

// Round 4
// 752.571 us; speedup vs baseline: 1.3002x; 1.3002x over previous
//
#include <hip/hip_runtime.h>

#define N_NODES 100000
#define N_EDGES 1600000
#define D_IN    256
#define D_HID   64
#define D_OUT   40
#define PROP_N  16

typedef short short8 __attribute__((ext_vector_type(8)));   // 8 bf16 (4 VGPRs)
typedef float f32x4  __attribute__((ext_vector_type(4)));   // MFMA accumulator

// ---- fp8 (OCP e4m3) helpers: HW convert, RNE, saturating ------------------
__device__ __forceinline__ unsigned char f32_to_fp8(float f) {
    int p = __builtin_amdgcn_cvt_pk_fp8_f32(f, f, 0, false);
    return (unsigned char)(p & 0xff);
}
// ---- bf16 helpers (RNE) ---------------------------------------------------
__device__ __forceinline__ unsigned short f32_to_bf16(float f) {
    unsigned int u = __float_as_uint(f);
    unsigned int r = (u + 0x7fffu + ((u >> 16) & 1u)) >> 16;
    return (unsigned short)r;
}
__device__ __forceinline__ unsigned int f32x2_to_bf16x2(float lo, float hi) {
    return (unsigned int)f32_to_bf16(lo) | ((unsigned int)f32_to_bf16(hi) << 16);
}
__device__ __forceinline__ float bf16_f(unsigned short u) {
    return __uint_as_float(((unsigned)u) << 16);
}
// decode packed edge: bits[31:15]=col, bits[14:0]=bf16(val) without sign
__device__ __forceinline__ float edge_val(unsigned p) {
    return __uint_as_float((p & 0x7fffu) << 16);
}
// 4-feature fp8 FMA: b holds 4 fp8 bytes
__device__ __forceinline__ void fma4(float4& a, float v, unsigned b) {
    a.x = fmaf(v, __builtin_amdgcn_cvt_f32_fp8((int)b, 0), a.x);
    a.y = fmaf(v, __builtin_amdgcn_cvt_f32_fp8((int)b, 1), a.y);
    a.z = fmaf(v, __builtin_amdgcn_cvt_f32_fp8((int)b, 2), a.z);
    a.w = fmaf(v, __builtin_amdgcn_cvt_f32_fp8((int)b, 3), a.w);
}

// ---------------------------------------------------------------------------
// Kernel 1: CSR row_ptr from sorted edge_row via binary search.
// ---------------------------------------------------------------------------
__global__ __launch_bounds__(256) void build_rowptr(const int* __restrict__ erow,
                                                    int* __restrict__ rp) {
    int r = blockIdx.x * blockDim.x + threadIdx.x;
    if (r > N_NODES) return;
    int lo = 0, hi = N_EDGES;
    while (lo < hi) {
        int mid = (lo + hi) >> 1;
        if (erow[mid] < r) lo = mid + 1; else hi = mid;
    }
    rp[r] = lo;
}

// ---------------------------------------------------------------------------
// Kernel 1b: pack (col, val) into ONE dword.
//   bits[31:15] = col (100000 < 2^17), bits[14:0] = bf16(val) sans sign.
// ---------------------------------------------------------------------------
__global__ __launch_bounds__(256) void pack_edges4(const int* __restrict__ ecol,
                                                   const float* __restrict__ evalv,
                                                   unsigned* __restrict__ ep4) {
    int i = blockIdx.x * blockDim.x + threadIdx.x;
    if (i >= N_EDGES) return;
    unsigned bf = f32_to_bf16(evalv[i]);
    ep4[i] = ((unsigned)ecol[i] << 15) | (bf & 0x7fffu);
}

// ---------------------------------------------------------------------------
// Kernel 1c: W1 [256][64] fp32 -> W1T [64][256] bf16 (for MFMA B-fragments).
// ---------------------------------------------------------------------------
__global__ __launch_bounds__(256) void prep_w1t(const float* __restrict__ W1,
                                                unsigned short* __restrict__ W1T) {
    int i = blockIdx.x * 256 + threadIdx.x;           // 16384 elements
    if (i >= D_IN * D_HID) return;
    int k = i >> 6, n = i & 63;
    W1T[n * 256 + k] = f32_to_bf16(W1[i]);
}

// ---------------------------------------------------------------------------
// Kernel 2 (MFMA): h = x @ W1 + b1. EXACT R0 core (61 us known-good; it sits
// at the per-CU outstanding-line cap -> ILP/occupancy restructures are null,
// two attempts confirmed). Epilogue now writes bf16 Y, bf16 src, fp8 Y8.
// ---------------------------------------------------------------------------
__global__ __launch_bounds__(64) void mlp1(const float* __restrict__ x,
                                           const unsigned short* __restrict__ W1T,
                                           const float* __restrict__ b1,
                                           const float* __restrict__ diag,
                                           unsigned short* __restrict__ Yb,
                                           unsigned char* __restrict__ Y08,
                                           unsigned short* __restrict__ srcb) {
    const int lane  = threadIdx.x;
    const int l15   = lane & 15;
    const int quad  = lane >> 4;
    const int mbase = blockIdx.x * 16;      // 6250 * 16 == 100000 exactly

    f32x4 acc[4] = {};
    const float* xrow = x + (size_t)(mbase + l15) * D_IN + quad * 8;

    #pragma unroll
    for (int ks = 0; ks < 8; ++ks) {
        float4 f0 = *(const float4*)(xrow + ks * 32);
        float4 f1 = *(const float4*)(xrow + ks * 32 + 4);
        union { short8 v; unsigned int u[4]; } a;
        a.u[0] = f32x2_to_bf16x2(f0.x, f0.y);
        a.u[1] = f32x2_to_bf16x2(f0.z, f0.w);
        a.u[2] = f32x2_to_bf16x2(f1.x, f1.y);
        a.u[3] = f32x2_to_bf16x2(f1.z, f1.w);

        #pragma unroll
        for (int ct = 0; ct < 4; ++ct) {
            short8 b = *(const short8*)(W1T + (ct * 16 + l15) * 256 + ks * 32 + quad * 8);
            acc[ct] = __builtin_amdgcn_mfma_f32_16x16x32_bf16(a.v, b, acc[ct], 0, 0, 0);
        }
    }

    float bias[4];
    #pragma unroll
    for (int ct = 0; ct < 4; ++ct) bias[ct] = b1[ct * 16 + l15];

    #pragma unroll
    for (int reg = 0; reg < 4; ++reg) {
        const int mr = mbase + quad * 4 + reg;
        const float dg = diag[mr];
        #pragma unroll
        for (int ct = 0; ct < 4; ++ct) {
            const int col = ct * 16 + l15;
            const float h = acc[ct][reg] + bias[ct];
            const size_t idx = (size_t)mr * 64 + col;
            Yb[idx]   = f32_to_bf16(h);
            srcb[idx] = f32_to_bf16(0.5f * dg * h);
            Y08[idx]  = f32_to_fp8(h);
        }
    }
}

// ---------------------------------------------------------------------------
// Kernel 3: one propagation step. R2 structure (known-best: 46.7 us/step),
// with the fp32 self/src/out streams converted to bf16. Per-step load-lines:
// gathers 1.6M (floor: 1 line/edge) + streams 0.9M -> 0.5M. Model: duration
// = load_lines x latency / (per-CU cap ~50) -> predict ~39 us/step.
// ---------------------------------------------------------------------------
__global__ __launch_bounds__(256) void prop_step(const unsigned short* __restrict__ Yb,
                                                 const unsigned char* __restrict__ Y8,
                                                 const unsigned short* __restrict__ srcb,
                                                 unsigned short* __restrict__ Ybo,
                                                 unsigned char* __restrict__ Yo8,
                                                 const int* __restrict__ rp,
                                                 const unsigned* __restrict__ ep4) {
    const int wid  = blockIdx.x * 4 + (threadIdx.x >> 6);   // 25000 waves
    const int lane = threadIdx.x & 63;
    const int g    = lane >> 4;         // row group 0..3
    const int fl   = lane & 15;         // feature-quad index
    const int row  = wid * 4 + g;       // exact: 100000 = 4 * 25000

    const int e0 = rp[row];
    const int e1 = rp[row + 1];

    const size_t fb = (size_t)row * 64 + fl * 4;
    const ushort4 ys4 = *(const ushort4*)(Yb + fb);      // 8B/lane
    const ushort4 sv4 = *(const ushort4*)(srcb + fb);
    const float4 yself = make_float4(bf16_f(ys4.x), bf16_f(ys4.y),
                                     bf16_f(ys4.z), bf16_f(ys4.w));
    const float4 sv    = make_float4(bf16_f(sv4.x), bf16_f(sv4.y),
                                     bf16_f(sv4.z), bf16_f(sv4.w));
    const unsigned char* Y8f = Y8 + fl * 4;

    float4 acc0 = make_float4(0.f, 0.f, 0.f, 0.f);
    float4 acc1 = acc0, acc2 = acc0, acc3 = acc0;

    int e = e0;
    // scalar head until e is 4-aligned (16B-aligned uint4 loads)
    int ea = (e0 + 3) & ~3;
    if (ea > e1) ea = e1;
    for (; e < ea; ++e) {
        unsigned p = ep4[e];
        unsigned b = *(const unsigned*)(Y8f + ((size_t)(p >> 15) << 6));
        fma4(acc0, edge_val(p), b);
    }
    for (; e + 8 <= e1; e += 8) {
        uint4 pa = *(const uint4*)(ep4 + e);
        uint4 pb = *(const uint4*)(ep4 + e + 4);
        unsigned b0 = *(const unsigned*)(Y8f + ((size_t)(pa.x >> 15) << 6));
        unsigned b1 = *(const unsigned*)(Y8f + ((size_t)(pa.y >> 15) << 6));
        unsigned b2 = *(const unsigned*)(Y8f + ((size_t)(pa.z >> 15) << 6));
        unsigned b3 = *(const unsigned*)(Y8f + ((size_t)(pa.w >> 15) << 6));
        unsigned b4 = *(const unsigned*)(Y8f + ((size_t)(pb.x >> 15) << 6));
        unsigned b5 = *(const unsigned*)(Y8f + ((size_t)(pb.y >> 15) << 6));
        unsigned b6 = *(const unsigned*)(Y8f + ((size_t)(pb.z >> 15) << 6));
        unsigned b7 = *(const unsigned*)(Y8f + ((size_t)(pb.w >> 15) << 6));
        fma4(acc0, edge_val(pa.x), b0);
        fma4(acc1, edge_val(pa.y), b1);
        fma4(acc2, edge_val(pa.z), b2);
        fma4(acc3, edge_val(pa.w), b3);
        fma4(acc0, edge_val(pb.x), b4);
        fma4(acc1, edge_val(pb.y), b5);
        fma4(acc2, edge_val(pb.z), b6);
        fma4(acc3, edge_val(pb.w), b7);
    }
    if (e + 4 <= e1) {
        uint4 pa = *(const uint4*)(ep4 + e);
        unsigned b0 = *(const unsigned*)(Y8f + ((size_t)(pa.x >> 15) << 6));
        unsigned b1 = *(const unsigned*)(Y8f + ((size_t)(pa.y >> 15) << 6));
        unsigned b2 = *(const unsigned*)(Y8f + ((size_t)(pa.z >> 15) << 6));
        unsigned b3 = *(const unsigned*)(Y8f + ((size_t)(pa.w >> 15) << 6));
        fma4(acc0, edge_val(pa.x), b0);
        fma4(acc1, edge_val(pa.y), b1);
        fma4(acc2, edge_val(pa.z), b2);
        fma4(acc3, edge_val(pa.w), b3);
        e += 4;
    }
    for (; e < e1; ++e) {
        unsigned p = ep4[e];
        unsigned b = *(const unsigned*)(Y8f + ((size_t)(p >> 15) << 6));
        fma4(acc0, edge_val(p), b);
    }

    float4 accs;
    accs.x = (acc0.x + acc1.x) + (acc2.x + acc3.x);
    accs.y = (acc0.y + acc1.y) + (acc2.y + acc3.y);
    accs.z = (acc0.z + acc1.z) + (acc2.z + acc3.z);
    accs.w = (acc0.w + acc1.w) + (acc2.w + acc3.w);

    float4 o;
    o.x = fmaf(0.5f, yself.x, fmaf(0.5f, accs.x, sv.x));
    o.y = fmaf(0.5f, yself.y, fmaf(0.5f, accs.y, sv.y));
    o.z = fmaf(0.5f, yself.z, fmaf(0.5f, accs.z, sv.z));
    o.w = fmaf(0.5f, yself.w, fmaf(0.5f, accs.w, sv.w));

    ushort4 ob;
    ob.x = f32_to_bf16(o.x); ob.y = f32_to_bf16(o.y);
    ob.z = f32_to_bf16(o.z); ob.w = f32_to_bf16(o.w);
    *(ushort4*)(Ybo + fb) = ob;
    int pk = __builtin_amdgcn_cvt_pk_fp8_f32(o.x, o.y, 0, false);   // bytes 0,1
    pk     = __builtin_amdgcn_cvt_pk_fp8_f32(o.z, o.w, pk, true);   // bytes 2,3
    *(unsigned*)(Yo8 + fb) = (unsigned)pk;
}

// ---------------------------------------------------------------------------
// Kernel 4: out = relu(Y) @ W2 + b2. Y now bf16 (uint4 = 8 features/load).
// ---------------------------------------------------------------------------
__global__ __launch_bounds__(256) void mlp2(const unsigned short* __restrict__ Yb,
                                            const float* __restrict__ W2,
                                            const float* __restrict__ b2,
                                            float* __restrict__ out) {
    __shared__ float W2s[D_HID * D_OUT];
    __shared__ float b2s[D_OUT];
    int tid = threadIdx.x;
    for (int i = tid; i < D_HID * D_OUT; i += 256) W2s[i] = W2[i];
    if (tid < D_OUT) b2s[tid] = b2[tid];
    __syncthreads();

    int n = blockIdx.x * 256 + tid;
    if (n >= N_NODES) return;

    float acc[D_OUT];
    #pragma unroll
    for (int o = 0; o < D_OUT; ++o) acc[o] = b2s[o];

    const uint4* Y4 = (const uint4*)(Yb + (size_t)n * 64);
    #pragma unroll
    for (int k8 = 0; k8 < 8; ++k8) {
        uint4 y = Y4[k8];
        unsigned w[4] = {y.x, y.y, y.z, y.w};
        #pragma unroll
        for (int d = 0; d < 4; ++d) {
            float lo = fmaxf(__uint_as_float((w[d] & 0xffffu) << 16), 0.0f);
            float hi = fmaxf(__uint_as_float(w[d] & 0xffff0000u), 0.0f);
            int klo = k8 * 8 + 2 * d, khi = klo + 1;
            #pragma unroll
            for (int o = 0; o < D_OUT; ++o)
                acc[o] = fmaf(lo, W2s[klo * D_OUT + o], acc[o]);
            #pragma unroll
            for (int o = 0; o < D_OUT; ++o)
                acc[o] = fmaf(hi, W2s[khi * D_OUT + o], acc[o]);
        }
    }

    float4* o4 = (float4*)(out + (size_t)n * D_OUT);
    #pragma unroll
    for (int q = 0; q < 10; ++q)
        o4[q] = make_float4(acc[4 * q], acc[4 * q + 1], acc[4 * q + 2], acc[4 * q + 3]);
}

// ---------------------------------------------------------------------------
extern "C" void kernel_launch(void* const* d_in, const int* in_sizes, int n_in,
                              void* d_out, int out_size, void* d_ws, size_t ws_size,
                              hipStream_t stream) {
    const float* x     = (const float*)d_in[0];
    const int*   erow  = (const int*)  d_in[1];
    const int*   ecol  = (const int*)  d_in[2];
    const float* evalv = (const float*)d_in[3];
    const float* diag  = (const float*)d_in[4];
    const float* W1    = (const float*)d_in[5];
    const float* b1    = (const float*)d_in[6];
    const float* W2    = (const float*)d_in[7];
    const float* b2    = (const float*)d_in[8];
    float* out = (float*)d_out;

    // workspace: Yb0|Yb1|srcb (bf16) | Y08|Y18 (fp8) | ep4 | rp | W1T
    const size_t NV = (size_t)N_NODES * D_HID;
    unsigned short* Yb0  = (unsigned short*)d_ws;
    unsigned short* Yb1  = Yb0 + NV;
    unsigned short* srcb = Yb1 + NV;
    unsigned char*  Y08  = (unsigned char*)(srcb + NV);
    unsigned char*  Y18  = Y08 + NV;
    unsigned*       ep4  = (unsigned*)(Y18 + NV);
    int*            rp   = (int*)(ep4 + N_EDGES);
    unsigned short* W1T  = (unsigned short*)
        (((unsigned long long)(rp + N_NODES + 1) + 15ull) & ~15ull);

    build_rowptr<<<(N_NODES + 1 + 255) / 256, 256, 0, stream>>>(erow, rp);
    pack_edges4<<<(N_EDGES + 255) / 256, 256, 0, stream>>>(ecol, evalv, ep4);
    prep_w1t<<<(D_IN * D_HID + 255) / 256, 256, 0, stream>>>(W1, W1T);
    mlp1<<<N_NODES / 16, 64, 0, stream>>>(x, W1T, b1, diag, Yb0, Y08, srcb);

    unsigned short* Yb[2] = {Yb0, Yb1};
    unsigned char*  Y8[2] = {Y08, Y18};
    for (int i = 0; i < PROP_N; ++i) {
        prop_step<<<N_NODES / 16, 256, 0, stream>>>(
            Yb[i & 1], Y8[i & 1], srcb, Yb[(i + 1) & 1], Y8[(i + 1) & 1], rp, ep4);
    }
    // PROP_N even -> final bf16 result in Yb0
    mlp2<<<(N_NODES + 255) / 256, 256, 0, stream>>>(Yb0, W2, b2, out);
}